// Round 1
// baseline (3854.093 us; speedup 1.0000x reference)
//
#include <hip/hip_runtime.h>
#include <hip/hip_bf16.h>

#define HID   1024
#define G3    3072
#define EMB   300
#define EMBP  320      // K padded to multiple of 32
#define VOCAB 3863
#define POSE  514
#define BATCH 128
#define TIN   64
#define TOUT  90

typedef __bf16 bf16x8 __attribute__((ext_vector_type(8)));
typedef float  f32x4  __attribute__((ext_vector_type(4)));
typedef __hip_bfloat16 bhalf;

#define MFMA(a,b,c) __builtin_amdgcn_mfma_f32_16x16x32_bf16((a),(b),(c),0,0,0)

// ---------- fp32 -> bf16 conversion with optional zero padding ----------
__global__ __launch_bounds__(256) void k_convert(const float* __restrict__ src,
        bhalf* __restrict__ dst, int rows_in, int cols_in, int cols_out, int total) {
  int i = blockIdx.x * 256 + threadIdx.x;
  if (i >= total) return;
  int r = i / cols_out, c = i - r * cols_out;
  float v = (r < rows_in && c < cols_in) ? src[(size_t)r * cols_in + c] : 0.f;
  dst[i] = __float2bfloat16(v);
}

// ---------- pack Whh [3H][H] -> [(j>>4)*48 + g*16 + (j&15)][k] bf16 ----------
__global__ __launch_bounds__(256) void k_pack(const float* __restrict__ whh,
                                              bhalf* __restrict__ dst) {
  int i = blockIdx.x * 256 + threadIdx.x;
  if (i >= G3 * HID) return;
  int k  = i & (HID - 1);
  int rp = i >> 10;           // packed row 0..3071
  int jg  = rp / 48;
  int rem = rp - jg * 48;
  int g = rem >> 4, jl = rem & 15;
  int j = (jg << 4) + jl;
  dst[i] = __float2bfloat16(whh[(size_t)((g << 10) + j) * HID + k]);
}

__global__ __launch_bounds__(256) void k_zero(float* a, float* b, bhalf* abf, bhalf* bbf) {
  int i = blockIdx.x * 256 + threadIdx.x;
  if (i >= BATCH * HID) return;
  a[i] = 0.f; b[i] = 0.f;
  bhalf z = __float2bfloat16(0.f);
  abf[i] = z; bbf[i] = z;
}

__global__ __launch_bounds__(256) void k_dech0(const float* __restrict__ hf,
        const float* __restrict__ hb, float* __restrict__ hd, bhalf* __restrict__ hdbf) {
  int i = blockIdx.x * 256 + threadIdx.x;
  if (i >= BATCH * HID) return;
  float s = hf[i] + hb[i];
  hd[i] = s;
  hdbf[i] = __float2bfloat16(s);
}

// ---------- generic MFMA GEMM-NT: C[M,Nstore] = A[M,K](bf16) @ B[N,K](bf16)^T + bias ----------
// block = 256 thr = 4 waves stacked on M; wave tile 32m x 32n.
// grid.x = N/32 tiles, grid.y = ceil(M/128).
__global__ __launch_bounds__(256) void k_gemm(
    const bhalf* __restrict__ A, const bhalf* __restrict__ B,
    const float* __restrict__ bias, float* __restrict__ C,
    int M, int K, int Nstore) {
  int tid = threadIdx.x;
  int l = tid & 63, w = tid >> 6;
  int q = l >> 4, jl = l & 15;
  int n0 = blockIdx.x * 32;
  int m0 = blockIdx.y * 128 + w * 32;
  int ar0 = m0 + jl;       if (ar0 >= M) ar0 = M - 1;   // clamp (stores are guarded)
  int ar1 = m0 + 16 + jl;  if (ar1 >= M) ar1 = M - 1;
  const bhalf* pa0 = A + (size_t)ar0 * K + q * 8;
  const bhalf* pa1 = A + (size_t)ar1 * K + q * 8;
  const bhalf* pb0 = B + (size_t)(n0 + jl) * K + q * 8;
  const bhalf* pb1 = B + (size_t)(n0 + 16 + jl) * K + q * 8;
  f32x4 acc[2][2] = {};
#pragma unroll 4
  for (int kc = 0; kc < K; kc += 32) {
    bf16x8 a0 = *(const bf16x8*)(pa0 + kc);
    bf16x8 a1 = *(const bf16x8*)(pa1 + kc);
    bf16x8 b0 = *(const bf16x8*)(pb0 + kc);
    bf16x8 b1 = *(const bf16x8*)(pb1 + kc);
    acc[0][0] = MFMA(a0, b0, acc[0][0]);
    acc[0][1] = MFMA(a0, b1, acc[0][1]);
    acc[1][0] = MFMA(a1, b0, acc[1][0]);
    acc[1][1] = MFMA(a1, b1, acc[1][1]);
  }
#pragma unroll
  for (int sub = 0; sub < 2; ++sub)
#pragma unroll
    for (int ns = 0; ns < 2; ++ns)
#pragma unroll
      for (int reg = 0; reg < 4; ++reg) {
        int row = m0 + sub * 16 + q * 4 + reg;
        int col = n0 + ns * 16 + jl;
        if (row < M && col < Nstore)
          C[(size_t)row * Nstore + col] = acc[sub][ns][reg] + bias[col];
      }
}

// ---------- fused GRU step: gh GEMM + gates + h update ----------
struct StepArgs {
  const bhalf* Bp;       // packed Whh [3072][1024]
  const float* tab;      // gi table [ntok][3072] (bih folded in)
  const float* bhh;      // [3072]
  const bhalf* hprev_bf; // [128][1024]
  const float* hprev_f;  // [128][1024]
  float*       hnext_f;
  bhalf*       hnext_bf;
  const int*   tok;      // token index base
  int tok_stride, tok_off;
};

// block = 128 thr = 2 waves; wave tile = 32m x (16 cols x 3 gates).
// grid = (64 j-groups, 2 m-halves, ndir)
__global__ __launch_bounds__(128) void k_step(StepArgs SA, StepArgs SB) {
  StepArgs S = (blockIdx.z == 0) ? SA : SB;
  int tid = threadIdx.x;
  int l = tid & 63, w = tid >> 6;
  int q = l >> 4, jl = l & 15;
  int jg = blockIdx.x;                 // 0..63
  int m0 = blockIdx.y * 64 + w * 32;   // 0,32,64,96
  int nb = jg * 48;
  const bhalf* pa0 = S.hprev_bf + (size_t)(m0 + jl) * HID + q * 8;
  const bhalf* pa1 = S.hprev_bf + (size_t)(m0 + 16 + jl) * HID + q * 8;
  const bhalf* pbr = S.Bp + (size_t)(nb + jl) * HID + q * 8;
  const bhalf* pbz = S.Bp + (size_t)(nb + 16 + jl) * HID + q * 8;
  const bhalf* pbn = S.Bp + (size_t)(nb + 32 + jl) * HID + q * 8;
  f32x4 acc[2][3] = {};
#pragma unroll 4
  for (int kc = 0; kc < HID; kc += 32) {
    bf16x8 a0 = *(const bf16x8*)(pa0 + kc);
    bf16x8 a1 = *(const bf16x8*)(pa1 + kc);
    bf16x8 br = *(const bf16x8*)(pbr + kc);
    bf16x8 bz = *(const bf16x8*)(pbz + kc);
    bf16x8 bn = *(const bf16x8*)(pbn + kc);
    acc[0][0] = MFMA(a0, br, acc[0][0]);
    acc[0][1] = MFMA(a0, bz, acc[0][1]);
    acc[0][2] = MFMA(a0, bn, acc[0][2]);
    acc[1][0] = MFMA(a1, br, acc[1][0]);
    acc[1][1] = MFMA(a1, bz, acc[1][1]);
    acc[1][2] = MFMA(a1, bn, acc[1][2]);
  }
  int j = (jg << 4) + jl;
  float bh_r = S.bhh[j];
  float bh_z = S.bhh[HID + j];
  float bh_n = S.bhh[2 * HID + j];
#pragma unroll
  for (int sub = 0; sub < 2; ++sub) {
#pragma unroll
    for (int reg = 0; reg < 4; ++reg) {
      int m = m0 + sub * 16 + q * 4 + reg;
      int tok = S.tok[m * S.tok_stride + S.tok_off];
      const float* gi = S.tab + (size_t)tok * G3;
      float hr = acc[sub][0][reg] + bh_r;
      float hz = acc[sub][1][reg] + bh_z;
      float hn = acc[sub][2][reg] + bh_n;
      float r = 1.f / (1.f + __expf(-(gi[j] + hr)));
      float z = 1.f / (1.f + __expf(-(gi[HID + j] + hz)));
      float n = tanhf(gi[2 * HID + j] + r * hn);
      float hp = S.hprev_f[(size_t)m * HID + j];
      float hv = (1.f - z) * n + z * hp;
      S.hnext_f[(size_t)m * HID + j] = hv;
      S.hnext_bf[(size_t)m * HID + j] = __float2bfloat16(hv);
    }
  }
}

extern "C" void kernel_launch(void* const* d_in, const int* in_sizes, int n_in,
                              void* d_out, int out_size, void* d_ws, size_t ws_size,
                              hipStream_t stream) {
  const float* enc_emb   = (const float*)d_in[0];
  const float* enc_Wih_f = (const float*)d_in[1];
  const float* enc_Whh_f = (const float*)d_in[2];
  const float* enc_bih_f = (const float*)d_in[3];
  const float* enc_bhh_f = (const float*)d_in[4];
  const float* enc_Wih_b = (const float*)d_in[5];
  const float* enc_Whh_b = (const float*)d_in[6];
  const float* enc_bih_b = (const float*)d_in[7];
  const float* enc_bhh_b = (const float*)d_in[8];
  const float* dec_emb   = (const float*)d_in[9];
  const float* dec_Wih   = (const float*)d_in[10];
  const float* dec_Whh   = (const float*)d_in[11];
  const float* dec_bih   = (const float*)d_in[12];
  const float* dec_bhh   = (const float*)d_in[13];
  const float* fc_W      = (const float*)d_in[14];
  const float* fc_b      = (const float*)d_in[15];
  const int*   in_text   = (const int*)d_in[16];
  const int*   poses     = (const int*)d_in[18];
  float* out = (float*)d_out;

  // ---- workspace carve-up (~163 MB) ----
  char* p = (char*)d_ws;
  auto alloc = [&](size_t n) { char* r = p; p += (n + 255) & ~(size_t)255; return r; };
  float* tabF = (float*)alloc((size_t)VOCAB * G3 * 4);
  float* tabB = (float*)alloc((size_t)VOCAB * G3 * 4);
  float* tabD = (float*)alloc((size_t)POSE * G3 * 4);
  float* hF[2], *hB[2], *hD[2];
  bhalf* hFbf[2], *hBbf[2];
  for (int i = 0; i < 2; ++i) {
    hF[i] = (float*)alloc(BATCH * HID * 4);
    hB[i] = (float*)alloc(BATCH * HID * 4);
    hD[i] = (float*)alloc(BATCH * HID * 4);
    hFbf[i] = (bhalf*)alloc(BATCH * HID * 2);
    hBbf[i] = (bhalf*)alloc(BATCH * HID * 2);
  }
  bhalf* hDbf0 = (bhalf*)alloc(BATCH * HID * 2);
  bhalf* hs    = (bhalf*)alloc((size_t)TOUT * BATCH * HID * 2);
  bhalf* embbf = (bhalf*)alloc((size_t)VOCAB * EMBP * 2);
  bhalf* wihF  = (bhalf*)alloc((size_t)G3 * EMBP * 2);
  bhalf* wihB  = (bhalf*)alloc((size_t)G3 * EMBP * 2);
  bhalf* dembbf= (bhalf*)alloc((size_t)POSE * HID * 2);
  bhalf* dwih  = (bhalf*)alloc((size_t)G3 * HID * 2);
  bhalf* fcw   = (bhalf*)alloc((size_t)544 * HID * 2);
  bhalf* packF = (bhalf*)alloc((size_t)G3 * HID * 2);
  bhalf* packB = (bhalf*)alloc((size_t)G3 * HID * 2);
  bhalf* packD = (bhalf*)alloc((size_t)G3 * HID * 2);

  auto cgrid = [](int total) { return dim3((total + 255) / 256); };

  // ---- conversions / packing (parallel, one-off) ----
  k_convert<<<cgrid(VOCAB * EMBP), 256, 0, stream>>>(enc_emb, embbf, VOCAB, EMB, EMBP, VOCAB * EMBP);
  k_convert<<<cgrid(G3 * EMBP),   256, 0, stream>>>(enc_Wih_f, wihF, G3, EMB, EMBP, G3 * EMBP);
  k_convert<<<cgrid(G3 * EMBP),   256, 0, stream>>>(enc_Wih_b, wihB, G3, EMB, EMBP, G3 * EMBP);
  k_convert<<<cgrid(POSE * HID),  256, 0, stream>>>(dec_emb, dembbf, POSE, HID, HID, POSE * HID);
  k_convert<<<cgrid(G3 * HID),    256, 0, stream>>>(dec_Wih, dwih, G3, HID, HID, G3 * HID);
  k_convert<<<cgrid(544 * HID),   256, 0, stream>>>(fc_W, fcw, POSE, HID, HID, 544 * HID);
  k_pack<<<cgrid(G3 * HID), 256, 0, stream>>>(enc_Whh_f, packF);
  k_pack<<<cgrid(G3 * HID), 256, 0, stream>>>(enc_Whh_b, packB);
  k_pack<<<cgrid(G3 * HID), 256, 0, stream>>>(dec_Whh, packD);
  k_zero<<<cgrid(BATCH * HID), 256, 0, stream>>>(hF[0], hB[0], hFbf[0], hBbf[0]);

  // ---- gi tables (bih folded) ----
  k_gemm<<<dim3(96, 31), 256, 0, stream>>>(embbf, wihF, enc_bih_f, tabF, VOCAB, EMBP, G3);
  k_gemm<<<dim3(96, 31), 256, 0, stream>>>(embbf, wihB, enc_bih_b, tabB, VOCAB, EMBP, G3);
  k_gemm<<<dim3(96, 5),  256, 0, stream>>>(dembbf, dwih, dec_bih, tabD, POSE, HID, G3);

  // ---- encoder: 64 steps, both directions fused per launch ----
  for (int t = 0; t < TIN; ++t) {
    int c = t & 1, nx = (t + 1) & 1;
    StepArgs af{packF, tabF, enc_bhh_f, hFbf[c], hF[c], hF[nx], hFbf[nx], in_text, TIN, t};
    StepArgs ab{packB, tabB, enc_bhh_b, hBbf[c], hB[c], hB[nx], hBbf[nx], in_text, TIN, t};
    k_step<<<dim3(64, 2, 2), 128, 0, stream>>>(af, ab);
  }
  // final enc hidden is in buffer index 64&1 = 0
  k_dech0<<<cgrid(BATCH * HID), 256, 0, stream>>>(hF[0], hB[0], hD[0], hDbf0);

  // ---- decoder: 90 steps; bf16 hidden written directly into hs slab ----
  for (int t = 0; t < TOUT; ++t) {
    int c = t & 1, nx = (t + 1) & 1;
    const bhalf* hpbf = (t == 0) ? hDbf0 : hs + (size_t)(t - 1) * BATCH * HID;
    StepArgs ad{packD, tabD, dec_bhh, hpbf, hD[c], hD[nx],
                hs + (size_t)t * BATCH * HID, poses, TOUT, (t == 0) ? 0 : (t - 1)};
    k_step<<<dim3(64, 2, 1), 128, 0, stream>>>(ad, ad);
  }

  // ---- output projection: out[t*B+b][o] = hs @ fc_W^T + fc_b ----
  k_gemm<<<dim3(17, 90), 256, 0, stream>>>(hs, fcw, fc_b, out, TOUT * BATCH, HID, POSE);
}